// Round 1
// baseline (338.636 us; speedup 1.0000x reference)
//
#include <hip/hip_runtime.h>
#include <hip/hip_bf16.h>

typedef short bf16x8 __attribute__((ext_vector_type(8)));
typedef float f32x4 __attribute__((ext_vector_type(4)));
typedef _Float16 f16x2 __attribute__((ext_vector_type(2)));

static __device__ __forceinline__ unsigned short f2bf_rne(float f) {
    unsigned int u = __float_as_uint(f);
    u += 0x7fff + ((u >> 16) & 1);
    return (unsigned short)(u >> 16);
}
static __device__ __forceinline__ float bf2f(unsigned short h) {
    return __uint_as_float(((unsigned int)h) << 16);
}

// split one fp32 weight element into hi/lo bf16 at its fragment-ordered slot
// B-frag layout for mfma_f32_16x16x32_bf16: lane=quad*16+(n&15) holds k=kc*32+quad*8+j
static __device__ __forceinline__ void wsplit_one(const float* W, unsigned short* hi,
                                                  unsigned short* lo, int BN, int idx) {
    int k = idx / BN, n = idx % BN;
    float w = W[idx];
    unsigned short h = f2bf_rne(w);
    unsigned short l = f2bf_rne(w - bf2f(h));
    int CT = BN >> 4;
    int kc = k >> 5, quad = (k >> 3) & 3, j = k & 7;
    int ct = n >> 4, c = n & 15;
    int slot = (((kc * CT + ct) * 4 + quad) * 16 + c) * 8 + j;
    hi[slot] = h;
    lo[slot] = l;
}

// ===================== GEMM body (BM=64 — R11 lesson: BM=128's 391 blocks = 1.5/CU
// load imbalance regressed; 782 blocks balance across 256 CUs) =====================
// R12: C is written QUARTER-MAJOR: t4[col>>5][node][col&31] fp16, so the aggregation
// can run as dim-quartered phase-local passes (3.2MB gather region -> per-XCD L2-resident).

template<int BN>
static __device__ __forceinline__ void gemm_body(const float* __restrict__ A,
                        const unsigned short* __restrict__ Whi, const unsigned short* __restrict__ Wlo,
                        _Float16* __restrict__ C, int N, int blk,
                        unsigned short* AhiS, unsigned short* AloS) {
    constexpr int CT = BN / 16;
    const int tid = threadIdx.x;
    const int wave = tid >> 6;
    const int lane = tid & 63;
    const int quad = lane >> 4;
    const int c16 = lane & 15;
    const int row0 = blk * 64;

    f32x4 acc[CT];
    #pragma unroll
    for (int t = 0; t < CT; ++t) acc[t] = (f32x4){0.f, 0.f, 0.f, 0.f};

    for (int kc = 0; kc < 4; ++kc) {
        #pragma unroll
        for (int r = 0; r < 2; ++r) {
            int f4 = tid + r * 256;
            int arow = f4 >> 3;
            int c4 = f4 & 7;
            int grow = row0 + arow;
            float4 v = make_float4(0.f, 0.f, 0.f, 0.f);
            if (grow < N) v = *(const float4*)&A[(size_t)grow * 128 + kc * 32 + c4 * 4];
            unsigned short h0 = f2bf_rne(v.x), h1 = f2bf_rne(v.y), h2 = f2bf_rne(v.z), h3 = f2bf_rne(v.w);
            ushort4 hv = make_ushort4(h0, h1, h2, h3);
            ushort4 lv = make_ushort4(f2bf_rne(v.x - bf2f(h0)), f2bf_rne(v.y - bf2f(h1)),
                                      f2bf_rne(v.z - bf2f(h2)), f2bf_rne(v.w - bf2f(h3)));
            int q = c4 >> 1;
            int joff = (c4 & 1) * 4;
            int base = (q * 64 + arow) * 8 + joff;
            *(ushort4*)&AhiS[base] = hv;
            *(ushort4*)&AloS[base] = lv;
        }
        __syncthreads();

        int abase = (quad * 64 + wave * 16 + c16) * 8;
        bf16x8 ahi = *(const bf16x8*)&AhiS[abase];
        bf16x8 alo = *(const bf16x8*)&AloS[abase];

        #pragma unroll
        for (int ct = 0; ct < CT; ++ct) {
            size_t bslot = ((size_t)(kc * CT + ct) * 64 + lane) * 8;
            bf16x8 bhi = *(const bf16x8*)&Whi[bslot];
            bf16x8 blo = *(const bf16x8*)&Wlo[bslot];
            acc[ct] = __builtin_amdgcn_mfma_f32_16x16x32_bf16(ahi, bhi, acc[ct], 0, 0, 0);
            acc[ct] = __builtin_amdgcn_mfma_f32_16x16x32_bf16(ahi, blo, acc[ct], 0, 0, 0);
            acc[ct] = __builtin_amdgcn_mfma_f32_16x16x32_bf16(alo, bhi, acc[ct], 0, 0, 0);
        }
        __syncthreads();
    }

    #pragma unroll
    for (int ct = 0; ct < CT; ++ct) {
        int col = ct * 16 + c16;
        _Float16* Cq = C + (size_t)(col >> 5) * N * 32 + (col & 31);
        #pragma unroll
        for (int r = 0; r < 4; ++r) {
            int grow = row0 + wave * 16 + quad * 4 + r;
            if (grow < N) Cq[(size_t)grow * 32] = (_Float16)acc[ct][r];
        }
    }
}

// ===================== preprocessing =====================

// phase 0: in-degree count + rank capture + weight split
__global__ __launch_bounds__(256) void k_count_wsplit(const int* __restrict__ dst, int* __restrict__ deg,
                          int* __restrict__ rank,
                          const float* __restrict__ W1, const float* __restrict__ W2, const float* __restrict__ W3,
                          unsigned short* __restrict__ W1hi, unsigned short* __restrict__ W1lo,
                          unsigned short* __restrict__ W2hi, unsigned short* __restrict__ W2lo,
                          unsigned short* __restrict__ W3hi, unsigned short* __restrict__ W3lo,
                          int E) {
    int e = blockIdx.x * blockDim.x + threadIdx.x;
    if (e < E) rank[e] = atomicAdd(&deg[dst[e]], 1);
    if (e < 128 * 128) {
        wsplit_one(W1, W1hi, W1lo, 128, e);
        wsplit_one(W2, W2hi, W2lo, 128, e);
    }
    if (e < 128 * 64) wsplit_one(W3, W3hi, W3lo, 64, e);
}

// single-kernel scan; also pre-fills out[] with bf (needed by the split-half final agg's
// cross-pass atomicAdd combine — zero extra dispatches, this kernel has >=N threads)
__global__ __launch_bounds__(1024) void k_scan(const int* __restrict__ deg, float* __restrict__ dinv,
                                               int* __restrict__ row_start,
                                               float* __restrict__ outp, const float* __restrict__ bf,
                                               int N) {
    __shared__ int s[1024];
    __shared__ int wsum[16];
    __shared__ int prefix;
    const int t = threadIdx.x;
    const int base = blockIdx.x * 1024;

    {
        int v = 0;
        for (int j = t; j < base; j += 1024) v += deg[j];
        for (int off = 32; off > 0; off >>= 1) v += __shfl_down(v, off, 64);
        if ((t & 63) == 0) wsum[t >> 6] = v;
        __syncthreads();
        if (t == 0) {
            int acc = 0;
            #pragma unroll
            for (int k = 0; k < 16; ++k) acc += wsum[k];
            prefix = acc;
        }
    }

    int i = base + t;
    int v = 0;
    if (i < N) {
        v = deg[i];
        dinv[i] = rsqrtf((float)v + 1.0f);
        outp[i] = bf[0];
    }
    s[t] = v;
    __syncthreads();
    for (int off = 1; off < 1024; off <<= 1) {
        int x = (t >= off) ? s[t - off] : 0;
        __syncthreads();
        s[t] += x;
        __syncthreads();
    }
    if (i <= N) row_start[i] = prefix + s[t] - v;   // row_start[N] = E via deg-past-N = 0
}

// ===================== fused: layer-1 GEMM + CSR scatter (independent work) =====================

__global__ __launch_bounds__(256, 2) void k_gemm1_scatter(const float* __restrict__ A,
                          const unsigned short* __restrict__ Whi, const unsigned short* __restrict__ Wlo,
                          _Float16* __restrict__ C, int N, int gemmGrid,
                          const int* __restrict__ src, const int* __restrict__ dst,
                          const int* __restrict__ row_start, const int* __restrict__ rank,
                          const float* __restrict__ dinv, int2* __restrict__ cv, int E) {
    __shared__ unsigned short AhiS[4 * 64 * 8];
    __shared__ unsigned short AloS[4 * 64 * 8];
    if ((int)blockIdx.x < gemmGrid) {
        gemm_body<128>(A, Whi, Wlo, C, N, blockIdx.x, AhiS, AloS);
    } else {
        int e = (blockIdx.x - gemmGrid) * 256 + threadIdx.x;
        if (e < E) {
            int d = dst[e];
            int s = src[e];
            cv[row_start[d] + rank[e]] = make_int2(s, __float_as_int(dinv[s]));
        }
    }
}

// plain GEMM kernels for layers 2/3
template<int BN>
__global__ __launch_bounds__(256, 2) void k_gemm_mfma(const float* __restrict__ A,
                        const unsigned short* __restrict__ Whi, const unsigned short* __restrict__ Wlo,
                        _Float16* __restrict__ C, int N) {
    __shared__ unsigned short AhiS[4 * 64 * 8];
    __shared__ unsigned short AloS[4 * 64 * 8];
    gemm_body<BN>(A, Whi, Wlo, C, N, blockIdx.x, AhiS, AloS);
}

// ===================== aggregation (R12: dim-quartered phase-local passes) =====================
// t stored quarter-major t4[q][node][32] fp16; one wave per (node, q). Pass q's gather region
// is N*32*2B = 3.2MB -> resident in each XCD's 4MB L2 (8x replicated). blockIdx is q-major
// (12500 blocks/pass vs ~2048 co-resident) so passes are phase-separated in time.
// Within a wave: 4 groups of 16 lanes; group g gathers 4 of each round's 16 rows with
// f16x2 (4B/lane, 64B row). Cross-group combine via shfl_xor(16,32) at the end.

__global__ __launch_bounds__(256) void k_agg128q(const _Float16* __restrict__ t, float* __restrict__ outp,
                      const int* __restrict__ row_start, const int2* __restrict__ cv,
                      const float* __restrict__ dinv, const float* __restrict__ bias,
                      int N) {
    int q = blockIdx.x / 12500;                               // const divisor -> magic mul
    int node = (blockIdx.x - q * 12500) * 4 + (threadIdx.x >> 6);
    int lane = threadIdx.x & 63;
    int l16 = lane & 15;
    int g4 = lane >> 4;
    const f16x2* tp = (const f16x2*)(t + (size_t)q * N * 32);
    int p = row_start[node];
    int end = row_start[node + 1];
    float2 accA = make_float2(0.f, 0.f);
    float2 accB = make_float2(0.f, 0.f);

    while (p < end) {
        int idx = p + lane;
        int2 h = (idx < end) ? cv[idx] : make_int2(0, 0);     // invalid lanes: s=0, w=0
        int cnt = min(end - p, 64);
        int rounds = (cnt + 15) >> 4;
        for (int r = 0; r < rounds; ++r) {
            int base = r * 16 + g4 * 4;
            int s0 = __shfl(h.x, base + 0, 64), s1 = __shfl(h.x, base + 1, 64);
            int s2 = __shfl(h.x, base + 2, 64), s3 = __shfl(h.x, base + 3, 64);
            float w0 = __int_as_float(__shfl(h.y, base + 0, 64));
            float w1 = __int_as_float(__shfl(h.y, base + 1, 64));
            float w2 = __int_as_float(__shfl(h.y, base + 2, 64));
            float w3 = __int_as_float(__shfl(h.y, base + 3, 64));
            f16x2 v0 = tp[s0 * 16 + l16];
            f16x2 v1 = tp[s1 * 16 + l16];
            f16x2 v2 = tp[s2 * 16 + l16];
            f16x2 v3 = tp[s3 * 16 + l16];
            accA.x += w0 * (float)v0.x; accA.y += w0 * (float)v0.y;
            accB.x += w1 * (float)v1.x; accB.y += w1 * (float)v1.y;
            accA.x += w2 * (float)v2.x; accA.y += w2 * (float)v2.y;
            accB.x += w3 * (float)v3.x; accB.y += w3 * (float)v3.y;
        }
        p += 64;
    }
    float sx = accA.x + accB.x;
    float sy = accA.y + accB.y;
    sx += __shfl_xor(sx, 16, 64); sx += __shfl_xor(sx, 32, 64);
    sy += __shfl_xor(sy, 16, 64); sy += __shfl_xor(sy, 32, 64);

    float di = dinv[node];
    f16x2 sv = tp[node * 16 + l16];
    float2 bv = ((const float2*)bias)[q * 16 + l16];
    float rx = fmaxf(di * sx + di * di * (float)sv.x + bv.x, 0.f);
    float ry = fmaxf(di * sy + di * di * (float)sv.y + bv.y, 0.f);
    if (lane < 16)
        ((float2*)outp)[(size_t)node * 64 + q * 16 + l16] = make_float2(rx, ry);
}

// layer-3 aggregation (D=64 split into 2 halves of 32 dims, region 3.2MB) fused with the
// final linear; halves combine via one fp32 atomicAdd per (node,half) into bf-prefilled out.
__global__ __launch_bounds__(256) void k_agg64_final(const _Float16* __restrict__ t, float* __restrict__ outp,
                      const int* __restrict__ row_start, const int2* __restrict__ cv,
                      const float* __restrict__ dinv, const float* __restrict__ bias,
                      const float* __restrict__ Wf,
                      int N) {
    int q = blockIdx.x / 12500;                               // 0..1
    int node = (blockIdx.x - q * 12500) * 4 + (threadIdx.x >> 6);
    int lane = threadIdx.x & 63;
    int l16 = lane & 15;
    int g4 = lane >> 4;
    const f16x2* tp = (const f16x2*)(t + (size_t)q * N * 32);
    int p = row_start[node];
    int end = row_start[node + 1];
    float2 accA = make_float2(0.f, 0.f);
    float2 accB = make_float2(0.f, 0.f);

    while (p < end) {
        int idx = p + lane;
        int2 h = (idx < end) ? cv[idx] : make_int2(0, 0);
        int cnt = min(end - p, 64);
        int rounds = (cnt + 15) >> 4;
        for (int r = 0; r < rounds; ++r) {
            int base = r * 16 + g4 * 4;
            int s0 = __shfl(h.x, base + 0, 64), s1 = __shfl(h.x, base + 1, 64);
            int s2 = __shfl(h.x, base + 2, 64), s3 = __shfl(h.x, base + 3, 64);
            float w0 = __int_as_float(__shfl(h.y, base + 0, 64));
            float w1 = __int_as_float(__shfl(h.y, base + 1, 64));
            float w2 = __int_as_float(__shfl(h.y, base + 2, 64));
            float w3 = __int_as_float(__shfl(h.y, base + 3, 64));
            f16x2 v0 = tp[s0 * 16 + l16];
            f16x2 v1 = tp[s1 * 16 + l16];
            f16x2 v2 = tp[s2 * 16 + l16];
            f16x2 v3 = tp[s3 * 16 + l16];
            accA.x += w0 * (float)v0.x; accA.y += w0 * (float)v0.y;
            accB.x += w1 * (float)v1.x; accB.y += w1 * (float)v1.y;
            accA.x += w2 * (float)v2.x; accA.y += w2 * (float)v2.y;
            accB.x += w3 * (float)v3.x; accB.y += w3 * (float)v3.y;
        }
        p += 64;
    }
    float sx = accA.x + accB.x;
    float sy = accA.y + accB.y;
    sx += __shfl_xor(sx, 16, 64); sx += __shfl_xor(sx, 32, 64);
    sy += __shfl_xor(sy, 16, 64); sy += __shfl_xor(sy, 32, 64);

    float di = dinv[node];
    f16x2 sv = tp[node * 16 + l16];
    float2 bv = ((const float2*)bias)[q * 16 + l16];
    float rx = fmaxf(di * sx + di * di * (float)sv.x + bv.x, 0.f);
    float ry = fmaxf(di * sy + di * di * (float)sv.y + bv.y, 0.f);
    float2 wf = ((const float2*)Wf)[q * 16 + l16];
    float partial = rx * wf.x + ry * wf.y;
    // sum within each 16-lane group (all 4 groups hold identical per-l16 values)
    partial += __shfl_xor(partial, 1, 64);
    partial += __shfl_xor(partial, 2, 64);
    partial += __shfl_xor(partial, 4, 64);
    partial += __shfl_xor(partial, 8, 64);
    if (lane == 0) atomicAdd(&outp[node], partial);
}

// ===================== launch =====================

extern "C" void kernel_launch(void* const* d_in, const int* in_sizes, int n_in,
                              void* d_out, int out_size, void* d_ws, size_t ws_size,
                              hipStream_t stream) {
    const float* x  = (const float*)d_in[0];
    const int*   src = (const int*)d_in[1];
    const int*   dst = (const int*)d_in[2];
    const float* W1 = (const float*)d_in[3];
    const float* b1 = (const float*)d_in[4];
    const float* W2 = (const float*)d_in[5];
    const float* b2 = (const float*)d_in[6];
    const float* W3 = (const float*)d_in[7];
    const float* b3 = (const float*)d_in[8];
    const float* Wf = (const float*)d_in[9];
    const float* bf = (const float*)d_in[10];
    float* out = (float*)d_out;

    const int N = 50000;
    const int E = 800000;

    char* ws = (char*)d_ws;
    size_t off = 0;
    auto alloc = [&](size_t bytes) -> void* {
        void* p = (void*)(ws + off);
        off += (bytes + 511) & ~((size_t)511);
        return p;
    };
    int*   deg       = (int*)alloc((size_t)N * 4);
    float* dinv      = (float*)alloc((size_t)N * 4);
    int*   row_start = (int*)alloc((size_t)(N + 1) * 4);
    int*   rank      = (int*)alloc((size_t)E * 4);
    int2*  cv        = (int2*)alloc((size_t)E * 8);
    _Float16* bufT   = (_Float16*)alloc((size_t)N * 128 * 2);   // GEMM out, quarter-major fp16
    float* bufH      = (float*)alloc((size_t)N * 128 * 4);      // agg out (GEMM input), fp32
    unsigned short* W1hi = (unsigned short*)alloc(128 * 128 * 2);
    unsigned short* W1lo = (unsigned short*)alloc(128 * 128 * 2);
    unsigned short* W2hi = (unsigned short*)alloc(128 * 128 * 2);
    unsigned short* W2lo = (unsigned short*)alloc(128 * 128 * 2);
    unsigned short* W3hi = (unsigned short*)alloc(128 * 64 * 2);
    unsigned short* W3lo = (unsigned short*)alloc(128 * 64 * 2);

    hipMemsetAsync(deg, 0, (size_t)N * 4, stream);

    k_count_wsplit<<<(E + 255) / 256, 256, 0, stream>>>(dst, deg, rank, W1, W2, W3,
                                                        W1hi, W1lo, W2hi, W2lo, W3hi, W3lo, E);
    int NB = (N + 1023) / 1024;   // 49 blocks
    k_scan<<<NB, 1024, 0, stream>>>(deg, dinv, row_start, out, bf, N);

    int gemmGrid = (N + 63) / 64;          // 782
    int scatGrid = (E + 255) / 256;        // 3125
    int agg128Grid = N;                    // 4N waves = (node, quarter), q-major
    int agg64Grid  = N / 2;                // 2N waves = (node, half), q-major

    // fused: layer-1 GEMM + scatter (independent work overlapped, one node saved)
    k_gemm1_scatter<<<gemmGrid + scatGrid, 256, 0, stream>>>(x, W1hi, W1lo, bufT, N, gemmGrid,
                                                             src, dst, row_start, rank, dinv, cv, E);
    k_agg128q<<<agg128Grid, 256, 0, stream>>>(bufT, bufH, row_start, cv, dinv, b1, N);
    // layer 2
    k_gemm_mfma<128><<<gemmGrid, 256, 0, stream>>>(bufH, W2hi, W2lo, bufT, N);
    k_agg128q<<<agg128Grid, 256, 0, stream>>>(bufT, bufH, row_start, cv, dinv, b2, N);
    // layer 3 (transform to 64 dims first, then split-half aggregate + fused final linear)
    k_gemm_mfma<64><<<gemmGrid, 256, 0, stream>>>(bufH, W3hi, W3lo, bufT, N);
    k_agg64_final<<<agg64Grid, 256, 0, stream>>>(bufT, out, row_start, cv, dinv, b3, Wf, N);
}